// Round 8
// baseline (186.980 us; speedup 1.0000x reference)
//
#include <hip/hip_runtime.h>
#include <math.h>

#define BB  16
#define TT  12
#define T2C 10
#define NN  300
#define DD  64
#define M3  900   // 3*NN
#define NW  (BB*T2C)

typedef _Float16 f16;
typedef __attribute__((ext_vector_type(8)))  _Float16 f16x8;
typedef __attribute__((ext_vector_type(16))) float    f32x16;

#define KS  72    // FFN Hl stride
#define SL  136   // 128-wide m-tiles stride (16B-aligned rows)

static __device__ inline unsigned pk2(f16 a, f16 b) {
    union { f16 h[2]; unsigned u; } x; x.h[0] = a; x.h[1] = b; return x.u;
}

// ---------------------------------------------------------------------------
// k_prep: blk < 960: fused norm + per-timestep ksum basis.
//         blk == 960: w1/w2 -> MFMA A-fragment order (fp16) in global.
// ---------------------------------------------------------------------------
__global__ __launch_bounds__(256) void k_prep(const float* __restrict__ feat,
                                              const float* __restrict__ weights,
                                              const float* __restrict__ w1,
                                              const float* __restrict__ w2,
                                              float* __restrict__ sigw,
                                              float* __restrict__ invn,
                                              float* __restrict__ tsum,
                                              f16* __restrict__ w1f,
                                              f16* __restrict__ w2f) {
    __shared__ float part[4][DD];
    int blk = blockIdx.x;
    int tid = threadIdx.x;

    if (blk == BB * TT * 5) {
        for (int p = tid; p < 1024; p += 256) {
            int lane = p & 63, s = p >> 6;
            int mat = s >> 3, loc = s & 7, ct = loc >> 2, ks = loc & 3;
            int hcol = ct * 32 + (lane & 31);
            const float* w = mat ? w2 : w1;
            f16* dst = (mat ? w2f : w1f) + ((size_t)loc * 64 + lane) * 8;
            f16x8 v;
            #pragma unroll
            for (int j = 0; j < 8; j++) {
                int d = ks * 16 + 8 * (lane >> 5) + j;
                v[j] = (f16)w[d * DD + hcol];
            }
            *(f16x8*)dst = v;
        }
        return;
    }

    int bt = blk / 5, ch = blk % 5;
    int row0 = bt * NN + ch * 60;
    int d = tid & 63, w = tid >> 6;

    float sg = 1.0f / (1.0f + expf(-weights[d]));
    if (blk == 0 && tid < 64) sigw[d] = sg;

    float acc = 0.f;
    for (int i = w; i < 60; i += 4) {
        int gr = row0 + i;
        float f = feat[(size_t)gr * DD + d];
        float x = f * sg;
        float ss = x * x;
        #pragma unroll
        for (int off = 32; off > 0; off >>= 1) ss += __shfl_xor(ss, off, 64);
        float in = 1.0f / fmaxf(sqrtf(ss), 1e-12f);
        if (d == 0) invn[gr] = in;
        acc += f * in;
    }
    part[w][d] = acc;
    __syncthreads();
    if (w == 0) {
        float v = (part[0][d] + part[1][d] + part[2][d] + part[3][d]) * sg;
        atomicAdd(&tsum[(size_t)bt * DD + d], v);
    }
}

// ---------------------------------------------------------------------------
// k_fused v3: 128-wide m-epochs (8 total), 2 barriers each.
//  pre-barrier:  stage Vt (feat*invn, transposed) + phase1 (K A-frags loaded
//                DIRECTLY from global -> 8 MFMA -> Sl[n][m])
//  post-barrier: phase2 (8 MFMA: acc += S.V)
// Then in-LDS FFN + residual + LayerNorm tail (r7, verified).
// ---------------------------------------------------------------------------
__global__ __launch_bounds__(256, 4) void k_fused(const float* __restrict__ feat,
                                                  const float* __restrict__ sigw,
                                                  const float* __restrict__ invn,
                                                  const float* __restrict__ tsum,
                                                  const f16* __restrict__ w1f,
                                                  const f16* __restrict__ w2f,
                                                  const float* __restrict__ b1,
                                                  const float* __restrict__ b2,
                                                  const float* __restrict__ gamma,
                                                  const float* __restrict__ beta,
                                                  float* __restrict__ out) {
    __shared__ union __align__(16) {
        struct __align__(16) {              // aggregation stage (~35 KB)
            f16 Vt[64 * SL];                // [d][m]  (feat*invn)
            f16 Sl[64 * SL];                // [n][m]
            float degp[64][4];
        } a;
        struct __align__(16) {              // FFN stage (~29.5 KB)
            float Ol[64 * 68];
            f16 Hl[64 * KS];
            float red[64][4][2];
            float rmax[64][4];
            float scls[64];
            float isls[64];
        } b;
    } U;
    __shared__ float degs[64];

    int blk = blockIdx.x;
    int wdw = blk % NW;     // XCD swizzle: a window's 5 blocks are 160 apart
    int rb  = blk / NW;
    int t2 = wdw % T2C, b = wdw / T2C;
    int n0 = rb * 64;
    int qrow0 = (b * TT + t2 + 2) * NN;
    int krow0 = (b * TT + t2) * NN;
    int tid = threadIdx.x;
    int wv = tid >> 6, lane = tid & 63;
    int l31 = lane & 31, lh = lane >> 5;
    int nt = wv & 1;   // n-block of this wave
    int dt = wv >> 1;  // d-block (phase2/output); also phase1 m-half selector

    // ---- deg partials: deg[n] = (feat[n]*sigw . ksum_w) * invn[n] ----
    {
        int r = tid >> 2, qd = (tid & 3) * 16;
        float p = 0.f;
        if (n0 + r < NN) {
            int gr = qrow0 + n0 + r;
            float in = invn[gr];
            const float4* f4 = (const float4*)(feat + (size_t)gr * DD + qd);
            const float4* s4 = (const float4*)(sigw + qd);
            const float4* t4 = (const float4*)(tsum + (size_t)(b * TT + t2) * DD + qd);
            #pragma unroll
            for (int i = 0; i < 4; i++) {
                float4 f = f4[i], s = s4[i];
                float4 k0 = t4[i], k1 = t4[i + 16], k2 = t4[i + 32];
                p += f.x * s.x * (k0.x + k1.x + k2.x) + f.y * s.y * (k0.y + k1.y + k2.y)
                   + f.z * s.z * (k0.z + k1.z + k2.z) + f.w * s.w * (k0.w + k1.w + k2.w);
            }
            p *= in;
        }
        U.a.degp[r][tid & 3] = p;
    }

    // ---- Q'' B-frags in registers: feat_q * sigw^2 * invn_q ----
    f16x8 qf[4];
    {
        int nloc = n0 + nt * 32 + l31;
        bool ok = nloc < NN;
        int gr = qrow0 + (ok ? nloc : 0);
        float in = ok ? invn[gr] : 0.f;
        #pragma unroll
        for (int ks = 0; ks < 4; ks++) {
            int c0 = ks * 16 + 8 * lh;
            float4 f0 = *(const float4*)(feat + (size_t)gr * DD + c0);
            float4 f1 = *(const float4*)(feat + (size_t)gr * DD + c0 + 4);
            float4 s0 = *(const float4*)(sigw + c0);
            float4 s1 = *(const float4*)(sigw + c0 + 4);
            f16x8 qv;
            qv[0] = (f16)(f0.x * s0.x * s0.x * in); qv[1] = (f16)(f0.y * s0.y * s0.y * in);
            qv[2] = (f16)(f0.z * s0.z * s0.z * in); qv[3] = (f16)(f0.w * s0.w * s0.w * in);
            qv[4] = (f16)(f1.x * s1.x * s1.x * in); qv[5] = (f16)(f1.y * s1.y * s1.y * in);
            qv[6] = (f16)(f1.z * s1.z * s1.z * in); qv[7] = (f16)(f1.w * s1.w * s1.w * in);
            qf[ks] = qv;
        }
    }
    __syncthreads();
    if (tid < 64)
        degs[tid] = U.a.degp[tid][0] + U.a.degp[tid][1]
                  + U.a.degp[tid][2] + U.a.degp[tid][3];

    f32x16 acc;
    #pragma unroll
    for (int i = 0; i < 16; i++) acc[i] = 0.f;

    for (int ep = 0; ep < 8; ep++) {
        int m0 = ep * 128;

        // ---- stage Vt: 512 units (64 m-pairs x 8 d-octs), 2 per thread ----
        #pragma unroll
        for (int uu = 0; uu < 2; uu++) {
            int u = tid + uu * 256;
            int pr = u & 63;            // m-pair
            int d8 = (u >> 6) * 8;      // d-oct
            int gm0 = m0 + 2 * pr, gm1 = gm0 + 1;
            bool ok0 = gm0 < M3, ok1 = gm1 < M3;
            const float* p0 = feat + (size_t)(krow0 + (ok0 ? gm0 : 0)) * DD + d8;
            const float* p1 = feat + (size_t)(krow0 + (ok1 ? gm1 : 0)) * DD + d8;
            float in0 = ok0 ? invn[krow0 + gm0] : 0.f;
            float in1 = ok1 ? invn[krow0 + gm1] : 0.f;
            float4 a0 = *(const float4*)p0, a1 = *(const float4*)(p0 + 4);
            float4 c0 = *(const float4*)p1, c1v = *(const float4*)(p1 + 4);
            float av[8] = {a0.x, a0.y, a0.z, a0.w, a1.x, a1.y, a1.z, a1.w};
            float cv[8] = {c0.x, c0.y, c0.z, c0.w, c1v.x, c1v.y, c1v.z, c1v.w};
            #pragma unroll
            for (int i = 0; i < 8; i++)
                *(unsigned*)&U.a.Vt[(d8 + i) * SL + 2 * pr] =
                    pk2((f16)(av[i] * in0), (f16)(cv[i] * in1));
        }

        // ---- phase1: K A-frags direct from global; S'' -> Sl[n][m] ----
        #pragma unroll
        for (int sub = 0; sub < 2; sub++) {
            int mrow = m0 + dt * 64 + sub * 32 + l31;
            bool okr = mrow < M3;
            float msk = okr ? 1.f : 0.f;
            const float* kp = feat + (size_t)(krow0 + (okr ? mrow : 0)) * DD;
            f32x16 c1;
            #pragma unroll
            for (int i = 0; i < 16; i++) c1[i] = 0.f;
            #pragma unroll
            for (int ks = 0; ks < 4; ks++) {
                float4 ka = *(const float4*)(kp + ks * 16 + 8 * lh);
                float4 kb = *(const float4*)(kp + ks * 16 + 8 * lh + 4);
                f16x8 af;
                af[0] = (f16)(ka.x * msk); af[1] = (f16)(ka.y * msk);
                af[2] = (f16)(ka.z * msk); af[3] = (f16)(ka.w * msk);
                af[4] = (f16)(kb.x * msk); af[5] = (f16)(kb.y * msk);
                af[6] = (f16)(kb.z * msk); af[7] = (f16)(kb.w * msk);
                c1 = __builtin_amdgcn_mfma_f32_32x32x16_f16(af, qf[ks], c1, 0, 0, 0);
            }
            int mbase = dt * 64 + sub * 32;
            #pragma unroll
            for (int g = 0; g < 4; g++) {
                union { f16 h[4]; uint2 u; } p;
                p.h[0] = (f16)c1[4 * g + 0]; p.h[1] = (f16)c1[4 * g + 1];
                p.h[2] = (f16)c1[4 * g + 2]; p.h[3] = (f16)c1[4 * g + 3];
                *(uint2*)&U.a.Sl[(nt * 32 + l31) * SL + mbase + 8 * g + 4 * lh] = p.u;
            }
        }
        __syncthreads();   // Vt + Sl produced

        // ---- phase2: acc(nt, dt) += S . V over m = 0..127 ----
        #pragma unroll
        for (int ms = 0; ms < 8; ms++) {
            f16x8 sa = *(const f16x8*)&U.a.Sl[(nt * 32 + l31) * SL + ms * 16 + 8 * lh];
            f16x8 vb = *(const f16x8*)&U.a.Vt[(dt * 32 + l31) * SL + ms * 16 + 8 * lh];
            acc = __builtin_amdgcn_mfma_f32_32x32x16_f16(sa, vb, acc, 0, 0, 0);
        }
        __syncthreads();   // consumers done; buffers free for next epoch
    }

    // ================= FFN stage (in-LDS handoff; r7-verified) =============
    int ct = wv & 1, rt = wv >> 1;
    f16x8 w1a[4], w2a[4];
    #pragma unroll
    for (int ks = 0; ks < 4; ks++) {
        w1a[ks] = *(const f16x8*)(w1f + ((size_t)(ct * 4 + ks) * 64 + lane) * 8);
        w2a[ks] = *(const f16x8*)(w2f + ((size_t)(ct * 4 + ks) * 64 + lane) * 8);
    }

    // agg = acc * dinv -> Ol[row][col] fp32
    {
        int dcol = dt * 32 + l31;
        #pragma unroll
        for (int g = 0; g < 4; g++) {
            #pragma unroll
            for (int i = 0; i < 4; i++) {
                int rl = nt * 32 + 8 * g + 4 * lh + i;
                float dg = degs[rl];
                float dinv = (dg == 0.f) ? 0.f : 1.f / dg;
                U.b.Ol[rl * 68 + dcol] = acc[4 * g + i] * dinv;
            }
        }
    }
    __syncthreads();

    int r = tid >> 2, q = tid & 3, c0 = q * 16;
    {
        float mx = 0.f;
        #pragma unroll
        for (int i = 0; i < 16; i += 4) {
            float4 f = *(const float4*)&U.b.Ol[r * 68 + c0 + i];
            mx = fmaxf(mx, fmaxf(fmaxf(fabsf(f.x), fabsf(f.y)),
                                 fmaxf(fabsf(f.z), fabsf(f.w))));
        }
        U.b.rmax[r][q] = mx;
    }
    __syncthreads();
    if (q == 0) {
        float rm = fmaxf(fmaxf(U.b.rmax[r][0], U.b.rmax[r][1]),
                         fmaxf(U.b.rmax[r][2], U.b.rmax[r][3]));
        int e = 0;
        frexpf(rm, &e);
        U.b.scls[r] = (rm > 1.f) ? exp2f((float)-e) : 1.f;
        U.b.isls[r] = (rm > 1.f) ? exp2f((float)e) : 1.f;
    }
    __syncthreads();

    // phase A: h_s^T = w1^T . A_s^T  (A_s read from Ol, scaled on the fly)
    float sclrow = U.b.scls[rt * 32 + l31];
    f32x16 hc;
    #pragma unroll
    for (int i = 0; i < 16; i++) hc[i] = 0.f;
    #pragma unroll
    for (int ks = 0; ks < 4; ks++) {
        const float* prow = &U.b.Ol[(rt * 32 + l31) * 68 + ks * 16 + 8 * lh];
        float4 pa = *(const float4*)prow;
        float4 pb = *(const float4*)(prow + 4);
        f16x8 bf;
        bf[0] = (f16)(pa.x * sclrow); bf[1] = (f16)(pa.y * sclrow);
        bf[2] = (f16)(pa.z * sclrow); bf[3] = (f16)(pa.w * sclrow);
        bf[4] = (f16)(pb.x * sclrow); bf[5] = (f16)(pb.y * sclrow);
        bf[6] = (f16)(pb.z * sclrow); bf[7] = (f16)(pb.w * sclrow);
        hc = __builtin_amdgcn_mfma_f32_32x32x16_f16(w1a[ks], bf, hc, 0, 0, 0);
    }
    #pragma unroll
    for (int g = 0; g < 4; g++) {
        union { f16 h[4]; uint2 u; } p;
        #pragma unroll
        for (int i = 0; i < 4; i++) {
            int hcol = ct * 32 + 8 * g + 4 * lh + i;
            p.h[i] = (f16)fmaxf(hc[4 * g + i] + sclrow * b1[hcol], 0.f);
        }
        *(uint2*)&U.b.Hl[(rt * 32 + l31) * KS + ct * 32 + 8 * g + 4 * lh] = p.u;
    }
    __syncthreads();

    // phase B: o_s^T = w2^T . h_s^T ; result overwrites Ol (agg dead)
    f32x16 oc;
    #pragma unroll
    for (int i = 0; i < 16; i++) oc[i] = 0.f;
    #pragma unroll
    for (int ks = 0; ks < 4; ks++) {
        f16x8 bf = *(const f16x8*)&U.b.Hl[(rt * 32 + l31) * KS + ks * 16 + 8 * lh];
        oc = __builtin_amdgcn_mfma_f32_32x32x16_f16(w2a[ks], bf, oc, 0, 0, 0);
    }
    __syncthreads();
    #pragma unroll
    for (int g = 0; g < 4; g++) {
        float4 o4 = make_float4(oc[4*g+0], oc[4*g+1], oc[4*g+2], oc[4*g+3]);
        *(float4*)&U.b.Ol[(rt * 32 + l31) * 68 + ct * 32 + 8 * g + 4 * lh] = o4;
    }
    __syncthreads();

    // epilogue: s = o_s/s_n + b2 + residual; LayerNorm; guarded store
    int n = n0 + r;
    int nn = (n < NN) ? n : (NN - 1);
    size_t frow = (size_t)(b * TT + t2 + 2) * NN + nn;
    float is = U.b.isls[r];
    float v[16];
    float sum = 0.f;
    #pragma unroll
    for (int i = 0; i < 16; i++) {
        int c = c0 + i;
        float x = U.b.Ol[r * 68 + c] * is + b2[c] + feat[frow * DD + c];
        v[i] = x; sum += x;
    }
    U.b.red[r][q][0] = sum;
    __syncthreads();
    float mu = (U.b.red[r][0][0] + U.b.red[r][1][0]
              + U.b.red[r][2][0] + U.b.red[r][3][0]) * (1.f / 64.f);
    float s2 = 0.f;
    #pragma unroll
    for (int i = 0; i < 16; i++) { float d = v[i] - mu; s2 += d * d; }
    U.b.red[r][q][1] = s2;
    __syncthreads();
    float var = (U.b.red[r][0][1] + U.b.red[r][1][1]
               + U.b.red[r][2][1] + U.b.red[r][3][1]) * (1.f / 64.f);
    float rs = rsqrtf(var + 1e-5f);
    if (n < NN) {
        size_t grow = (size_t)(b * T2C + t2) * NN + n;
        #pragma unroll
        for (int i4 = 0; i4 < 4; i4++) {
            int c = c0 + 4 * i4;
            float4 g4 = *(const float4*)(gamma + c);
            float4 be = *(const float4*)(beta + c);
            float4 o4;
            o4.x = (v[4*i4+0] - mu) * rs * g4.x + be.x;
            o4.y = (v[4*i4+1] - mu) * rs * g4.y + be.y;
            o4.z = (v[4*i4+2] - mu) * rs * g4.z + be.z;
            o4.w = (v[4*i4+3] - mu) * rs * g4.w + be.w;
            *(float4*)(out + grow * DD + c) = o4;
        }
    }
}

// ---------------------------------------------------------------------------
extern "C" void kernel_launch(void* const* d_in, const int* in_sizes, int n_in,
                              void* d_out, int out_size, void* d_ws, size_t ws_size,
                              hipStream_t stream) {
    const float* feat    = (const float*)d_in[0];
    const float* weights = (const float*)d_in[1];
    const float* w1      = (const float*)d_in[2];
    const float* b1      = (const float*)d_in[3];
    const float* w2      = (const float*)d_in[4];
    const float* b2      = (const float*)d_in[5];
    const float* gamma   = (const float*)d_in[6];
    const float* beta    = (const float*)d_in[7];
    float* out = (float*)d_out;

    float* sigw = (float*)d_ws;                 // 64
    float* invn = sigw + 64;                    // 57600
    float* tsum = invn + BB * TT * NN;          // 12288
    f16*   w1f  = (f16*)(tsum + BB * TT * DD);  // 4096 f16
    f16*   w2f  = w1f + 4096;                   // 4096 f16

    hipMemsetAsync(tsum, 0, (size_t)BB * TT * DD * sizeof(float), stream);
    k_prep<<<BB * TT * 5 + 1, 256, 0, stream>>>(feat, weights, w1, w2,
                                                sigw, invn, tsum, w1f, w2f);
    k_fused<<<NW * 5, 256, 0, stream>>>(feat, sigw, invn, tsum, w1f, w2f,
                                        b1, b2, gamma, beta, out);
}

// Round 9
// 144.207 us; speedup vs baseline: 1.2966x; 1.2966x over previous
//
#include <hip/hip_runtime.h>
#include <math.h>

#define BB  16
#define TT  12
#define T2C 10
#define NN  300
#define DD  64
#define M3  900   // 3*NN
#define NW  (BB*T2C)

typedef _Float16 f16;
typedef __attribute__((ext_vector_type(8)))  _Float16 f16x8;
typedef __attribute__((ext_vector_type(16))) float    f32x16;

#define KS 72   // fp16 row stride (144 B)

static __device__ inline unsigned pk2(f16 a, f16 b) {
    union { f16 h[2]; unsigned u; } x; x.h[0] = a; x.h[1] = b; return x.u;
}

// ---------------------------------------------------------------------------
// k_prep v2 (no atomics, no memset):
//  blk < 960: (bt, chunk of 60 rows). Waves process 4 rows/iter (16-lane
//  row-reduce) -> invn; per-chunk tsum partial -> tspart[blk][64].
//  blk == 960: sigw + w1/w2 -> MFMA A-fragment order (fp16) in global.
// ---------------------------------------------------------------------------
__global__ __launch_bounds__(256) void k_prep(const float* __restrict__ feat,
                                              const float* __restrict__ weights,
                                              const float* __restrict__ w1,
                                              const float* __restrict__ w2,
                                              float* __restrict__ sigw,
                                              float* __restrict__ invn,
                                              float* __restrict__ tspart,
                                              f16* __restrict__ w1f,
                                              f16* __restrict__ w2f) {
    int blk = blockIdx.x;
    int tid = threadIdx.x;

    if (blk == BB * TT * 5) {
        if (tid < 64) sigw[tid] = 1.0f / (1.0f + expf(-weights[tid]));
        for (int p = tid; p < 1024; p += 256) {
            int lane = p & 63, s = p >> 6;
            int mat = s >> 3, loc = s & 7, ct = loc >> 2, ks = loc & 3;
            int hcol = ct * 32 + (lane & 31);
            const float* w = mat ? w2 : w1;
            f16* dst = (mat ? w2f : w1f) + ((size_t)loc * 64 + lane) * 8;
            f16x8 v;
            #pragma unroll
            for (int j = 0; j < 8; j++) {
                int d = ks * 16 + 8 * (lane >> 5) + j;
                v[j] = (f16)w[d * DD + hcol];
            }
            *(f16x8*)dst = v;
        }
        return;
    }

    __shared__ float part[4][64];
    int bt = blk / 5, ch = blk % 5;
    int row0 = bt * NN + ch * 60;
    int w = tid >> 6, lane = tid & 63;
    int r16 = lane >> 4, c4 = lane & 15;

    // per-lane sigmoid for its 4 columns
    float4 wv = *(const float4*)(weights + c4 * 4);
    float4 sg;
    sg.x = 1.0f / (1.0f + expf(-wv.x)); sg.y = 1.0f / (1.0f + expf(-wv.y));
    sg.z = 1.0f / (1.0f + expf(-wv.z)); sg.w = 1.0f / (1.0f + expf(-wv.w));

    float ax = 0.f, ay = 0.f, az = 0.f, aw = 0.f;
    for (int g = w; g < 15; g += 4) {          // group = 4 rows; lanes cover 4x64
        int row = row0 + g * 4 + r16;
        float4 f = *(const float4*)(feat + (size_t)row * DD + c4 * 4);
        float xx = f.x * sg.x, xy = f.y * sg.y, xz = f.z * sg.z, xw = f.w * sg.w;
        float ss = xx * xx + xy * xy + xz * xz + xw * xw;
        ss += __shfl_xor(ss, 1, 64);
        ss += __shfl_xor(ss, 2, 64);
        ss += __shfl_xor(ss, 4, 64);
        ss += __shfl_xor(ss, 8, 64);
        float in = 1.0f / fmaxf(sqrtf(ss), 1e-12f);
        if (c4 == 0) invn[row] = in;
        ax += f.x * in; ay += f.y * in; az += f.z * in; aw += f.w * in;
    }
    // combine the 4 row-groups (lanes sharing c4): xor 16, 32
    #pragma unroll
    for (int off = 16; off <= 32; off <<= 1) {
        ax += __shfl_xor(ax, off, 64); ay += __shfl_xor(ay, off, 64);
        az += __shfl_xor(az, off, 64); aw += __shfl_xor(aw, off, 64);
    }
    if (r16 == 0) {
        float* p = &part[w][c4 * 4];
        p[0] = ax * sg.x; p[1] = ay * sg.y; p[2] = az * sg.z; p[3] = aw * sg.w;
    }
    __syncthreads();
    if (tid < 64)
        tspart[(size_t)blk * 64 + tid] =
            part[0][tid] + part[1][tid] + part[2][tid] + part[3][tid];
}

// ---------------------------------------------------------------------------
// k_fused: r7-verified agg loop, 3 barriers/kt (Vt staging merged into Kf
// staging) + in-LDS FFN/LayerNorm tail + XCD swizzle.
// deg basis: ksumL = sum of 15 tspart chunk rows (fp32, coalesced).
// ---------------------------------------------------------------------------
__global__ __launch_bounds__(256) void k_fused(const float* __restrict__ feat,
                                               const float* __restrict__ sigw,
                                               const float* __restrict__ invn,
                                               const float* __restrict__ tspart,
                                               const f16* __restrict__ w1f,
                                               const f16* __restrict__ w2f,
                                               const float* __restrict__ b1,
                                               const float* __restrict__ b2,
                                               const float* __restrict__ gamma,
                                               const float* __restrict__ beta,
                                               float* __restrict__ out) {
    __shared__ union __align__(16) {
        struct __align__(16) {              // aggregation stage (~28.7 KB)
            f16 Kf[64 * KS];
            f16 Vt[64 * KS];
            f16 Sl[64 * KS];
            float degp[64][4];
        } a;
        struct __align__(16) {              // FFN stage (~30.2 KB)
            float Ol[64 * 68];
            f16 Hl[64 * KS];
            float red[64][4][2];
            float rmax[64][4];
            float scls[64];
            float isls[64];
        } b;
    } U;
    __shared__ float degs[64];
    __shared__ float ksumL[64];

    int blk = blockIdx.x;
    int wdw = blk % NW;    // XCD swizzle: a window's 5 blocks are 160 apart
    int rb  = blk / NW;
    int t2 = wdw % T2C, b = wdw / T2C;
    int n0 = rb * 64;
    int qrow0 = (b * TT + t2 + 2) * NN;
    int krow0 = (b * TT + t2) * NN;
    int tid = threadIdx.x;
    int wv = tid >> 6, lane = tid & 63;
    int l31 = lane & 31, lh = lane >> 5;
    int nt = wv & 1;   // phase1 n-block == phase2 row-block
    int mt = wv >> 1;  // phase1 m-tile  == phase2 d-block

    // ---- ksumL[d] = sum of the window's 15 tspart chunk rows (fp32) ----
    if (tid < 64) {
        const float* tp = tspart + (size_t)(b * TT + t2) * 5 * 64 + tid;
        float s = 0.f;
        #pragma unroll
        for (int j = 0; j < 15; j++) s += tp[j * 64];
        ksumL[tid] = s;
    }

    // ---- Q'' B-frags in registers: feat_q * sigw^2 * invn_q ----
    f16x8 qf[4];
    {
        int nloc = n0 + nt * 32 + l31;
        bool ok = nloc < NN;
        int gr = qrow0 + (ok ? nloc : 0);
        float in = ok ? invn[gr] : 0.f;
        #pragma unroll
        for (int ks = 0; ks < 4; ks++) {
            int c0 = ks * 16 + 8 * lh;
            float4 f0 = *(const float4*)(feat + (size_t)gr * DD + c0);
            float4 f1 = *(const float4*)(feat + (size_t)gr * DD + c0 + 4);
            float4 s0 = *(const float4*)(sigw + c0);
            float4 s1 = *(const float4*)(sigw + c0 + 4);
            f16x8 qv;
            qv[0] = (f16)(f0.x * s0.x * s0.x * in); qv[1] = (f16)(f0.y * s0.y * s0.y * in);
            qv[2] = (f16)(f0.z * s0.z * s0.z * in); qv[3] = (f16)(f0.w * s0.w * s0.w * in);
            qv[4] = (f16)(f1.x * s1.x * s1.x * in); qv[5] = (f16)(f1.y * s1.y * s1.y * in);
            qv[6] = (f16)(f1.z * s1.z * s1.z * in); qv[7] = (f16)(f1.w * s1.w * s1.w * in);
            qf[ks] = qv;
        }
    }
    __syncthreads();   // ksumL visible

    // ---- deg partials: deg[n] = (feat[n]*sigw . ksumL) * invn[n] ----
    {
        int r = tid >> 2, qd = (tid & 3) * 16;
        float p = 0.f;
        if (n0 + r < NN) {
            int gr = qrow0 + n0 + r;
            float in = invn[gr];
            const float4* f4 = (const float4*)(feat + (size_t)gr * DD + qd);
            const float4* s4 = (const float4*)(sigw + qd);
            const float4* k4 = (const float4*)(ksumL + qd);
            #pragma unroll
            for (int i = 0; i < 4; i++) {
                float4 f = f4[i], s = s4[i], k = k4[i];
                p += f.x * s.x * k.x + f.y * s.y * k.y
                   + f.z * s.z * k.z + f.w * s.w * k.w;
            }
            p *= in;
        }
        U.a.degp[r][tid & 3] = p;
    }
    __syncthreads();
    if (tid < 64)
        degs[tid] = U.a.degp[tid][0] + U.a.degp[tid][1]
                  + U.a.degp[tid][2] + U.a.degp[tid][3];

    f32x16 acc;
    #pragma unroll
    for (int i = 0; i < 16; i++) acc[i] = 0.f;

    int mrow_s = (tid & 31) * 2;     // staging m-pair
    int dblk_s = (tid >> 5) * 8;     // staging 8-col block

    for (int kt = 0; kt < 15; kt++) {
        int m0 = kt * 64;
        __syncthreads();             // prev phase2 done with Kf/Vt/Sl (kt=0: degs)

        // ---- stage Kf (raw feat fp16) + Vt (feat*invn transposed) ----
        #pragma unroll
        for (int pi = 0; pi < 2; pi++) {
            int mloc = mrow_s + pi, gm = m0 + mloc;
            float4 fa = make_float4(0, 0, 0, 0), fb = make_float4(0, 0, 0, 0);
            float in = 0.f;
            if (gm < M3) {
                int gr = krow0 + gm;
                in = invn[gr];
                fa = *(const float4*)(feat + (size_t)gr * DD + dblk_s);
                fb = *(const float4*)(feat + (size_t)gr * DD + dblk_s + 4);
            }
            f16x8 kr;
            kr[0] = (f16)fa.x; kr[1] = (f16)fa.y; kr[2] = (f16)fa.z; kr[3] = (f16)fa.w;
            kr[4] = (f16)fb.x; kr[5] = (f16)fb.y; kr[6] = (f16)fb.z; kr[7] = (f16)fb.w;
            *(f16x8*)&U.a.Kf[mloc * KS + dblk_s] = kr;
            if (pi == 0) {
                // hold row0 scaled values, write pairs after row1 is ready
                float v0[8] = {fa.x * in, fa.y * in, fa.z * in, fa.w * in,
                               fb.x * in, fb.y * in, fb.z * in, fb.w * in};
                #pragma unroll
                for (int i = 0; i < 8; i++)
                    ((float*)&U.a.degp[0][0])[0] = ((float*)&U.a.degp[0][0])[0]; // no-op placeholder
                // stash in registers via locals (compiler keeps them)
                // (handled below by recomputing in second pass)
                #pragma unroll
                for (int i = 0; i < 8; i++) {
                    // store scaled row0 temporarily into Vt as lo halves
                    U.a.Vt[(dblk_s + i) * KS + mrow_s] = (f16)v0[i];
                }
            } else {
                float v1[8] = {fa.x * in, fa.y * in, fa.z * in, fa.w * in,
                               fb.x * in, fb.y * in, fb.z * in, fb.w * in};
                #pragma unroll
                for (int i = 0; i < 8; i++)
                    U.a.Vt[(dblk_s + i) * KS + mrow_s + 1] = (f16)v1[i];
            }
        }
        __syncthreads();             // Kf + Vt staged

        // ---- phase1: S''^T tile (m-rows mt*32.., n-cols nt*32..) ----
        f32x16 c1;
        #pragma unroll
        for (int i = 0; i < 16; i++) c1[i] = 0.f;
        #pragma unroll
        for (int ks = 0; ks < 4; ks++) {
            f16x8 af = *(const f16x8*)&U.a.Kf[(mt * 32 + l31) * KS + ks * 16 + 8 * lh];
            c1 = __builtin_amdgcn_mfma_f32_32x32x16_f16(af, qf[ks], c1, 0, 0, 0);
        }
        #pragma unroll
        for (int g = 0; g < 4; g++) {
            union { f16 h[4]; uint2 u; } p;
            p.h[0] = (f16)c1[4 * g + 0]; p.h[1] = (f16)c1[4 * g + 1];
            p.h[2] = (f16)c1[4 * g + 2]; p.h[3] = (f16)c1[4 * g + 3];
            *(uint2*)&U.a.Sl[(nt * 32 + l31) * KS + mt * 32 + 8 * g + 4 * lh] = p.u;
        }
        __syncthreads();             // Sl visible

        // ---- phase2: acc(n-block nt, d-block mt) += S . V ----
        #pragma unroll
        for (int ms = 0; ms < 4; ms++) {
            f16x8 sa = *(const f16x8*)&U.a.Sl[(nt * 32 + l31) * KS + ms * 16 + 8 * lh];
            f16x8 vb = *(const f16x8*)&U.a.Vt[(mt * 32 + l31) * KS + ms * 16 + 8 * lh];
            acc = __builtin_amdgcn_mfma_f32_32x32x16_f16(sa, vb, acc, 0, 0, 0);
        }
    }
    __syncthreads();                 // agg stage done; union switches to FFN

    // ================= FFN stage (in-LDS handoff; r7-verified) =============
    int ct = wv & 1, rt = wv >> 1;
    f16x8 w1a[4], w2a[4];
    #pragma unroll
    for (int ks = 0; ks < 4; ks++) {
        w1a[ks] = *(const f16x8*)(w1f + ((size_t)(ct * 4 + ks) * 64 + lane) * 8);
        w2a[ks] = *(const f16x8*)(w2f + ((size_t)(ct * 4 + ks) * 64 + lane) * 8);
    }

    // agg = acc * dinv -> Ol[row][col] fp32
    {
        int dcol = mt * 32 + l31;
        #pragma unroll
        for (int g = 0; g < 4; g++) {
            #pragma unroll
            for (int i = 0; i < 4; i++) {
                int rl = nt * 32 + 8 * g + 4 * lh + i;
                float dg = degs[rl];
                float dinv = (dg == 0.f) ? 0.f : 1.f / dg;
                U.b.Ol[rl * 68 + dcol] = acc[4 * g + i] * dinv;
            }
        }
    }
    __syncthreads();

    int r = tid >> 2, q = tid & 3, c0 = q * 16;
    {
        float mx = 0.f;
        #pragma unroll
        for (int i = 0; i < 16; i += 4) {
            float4 f = *(const float4*)&U.b.Ol[r * 68 + c0 + i];
            mx = fmaxf(mx, fmaxf(fmaxf(fabsf(f.x), fabsf(f.y)),
                                 fmaxf(fabsf(f.z), fabsf(f.w))));
        }
        U.b.rmax[r][q] = mx;
    }
    __syncthreads();
    if (q == 0) {
        float rm = fmaxf(fmaxf(U.b.rmax[r][0], U.b.rmax[r][1]),
                         fmaxf(U.b.rmax[r][2], U.b.rmax[r][3]));
        int e = 0;
        frexpf(rm, &e);
        U.b.scls[r] = (rm > 1.f) ? exp2f((float)-e) : 1.f;
        U.b.isls[r] = (rm > 1.f) ? exp2f((float)e) : 1.f;
    }
    __syncthreads();

    // phase A: h_s^T = w1^T . A_s^T  (A_s read from Ol, scaled on the fly)
    float sclrow = U.b.scls[rt * 32 + l31];
    f32x16 hc;
    #pragma unroll
    for (int i = 0; i < 16; i++) hc[i] = 0.f;
    #pragma unroll
    for (int ks = 0; ks < 4; ks++) {
        const float* prow = &U.b.Ol[(rt * 32 + l31) * 68 + ks * 16 + 8 * lh];
        float4 pa = *(const float4*)prow;
        float4 pb = *(const float4*)(prow + 4);
        f16x8 bf;
        bf[0] = (f16)(pa.x * sclrow); bf[1] = (f16)(pa.y * sclrow);
        bf[2] = (f16)(pa.z * sclrow); bf[3] = (f16)(pa.w * sclrow);
        bf[4] = (f16)(pb.x * sclrow); bf[5] = (f16)(pb.y * sclrow);
        bf[6] = (f16)(pb.z * sclrow); bf[7] = (f16)(pb.w * sclrow);
        hc = __builtin_amdgcn_mfma_f32_32x32x16_f16(w1a[ks], bf, hc, 0, 0, 0);
    }
    #pragma unroll
    for (int g = 0; g < 4; g++) {
        union { f16 h[4]; uint2 u; } p;
        #pragma unroll
        for (int i = 0; i < 4; i++) {
            int hcol = ct * 32 + 8 * g + 4 * lh + i;
            p.h[i] = (f16)fmaxf(hc[4 * g + i] + sclrow * b1[hcol], 0.f);
        }
        *(uint2*)&U.b.Hl[(rt * 32 + l31) * KS + ct * 32 + 8 * g + 4 * lh] = p.u;
    }
    __syncthreads();

    // phase B: o_s^T = w2^T . h_s^T ; result overwrites Ol (agg dead)
    f32x16 oc;
    #pragma unroll
    for (int i = 0; i < 16; i++) oc[i] = 0.f;
    #pragma unroll
    for (int ks = 0; ks < 4; ks++) {
        f16x8 bf = *(const f16x8*)&U.b.Hl[(rt * 32 + l31) * KS + ks * 16 + 8 * lh];
        oc = __builtin_amdgcn_mfma_f32_32x32x16_f16(w2a[ks], bf, oc, 0, 0, 0);
    }
    __syncthreads();
    #pragma unroll
    for (int g = 0; g < 4; g++) {
        float4 o4 = make_float4(oc[4*g+0], oc[4*g+1], oc[4*g+2], oc[4*g+3]);
        *(float4*)&U.b.Ol[(rt * 32 + l31) * 68 + ct * 32 + 8 * g + 4 * lh] = o4;
    }
    __syncthreads();

    // epilogue: s = o_s/s_n + b2 + residual; LayerNorm; guarded store
    int n = n0 + r;
    int nn = (n < NN) ? n : (NN - 1);
    size_t frow = (size_t)(b * TT + t2 + 2) * NN + nn;
    float is = U.b.isls[r];
    float v[16];
    float sum = 0.f;
    #pragma unroll
    for (int i = 0; i < 16; i++) {
        int c = c0 + i;
        float x = U.b.Ol[r * 68 + c] * is + b2[c] + feat[frow * DD + c];
        v[i] = x; sum += x;
    }
    U.b.red[r][q][0] = sum;
    __syncthreads();
    float mu = (U.b.red[r][0][0] + U.b.red[r][1][0]
              + U.b.red[r][2][0] + U.b.red[r][3][0]) * (1.f / 64.f);
    float s2 = 0.f;
    #pragma unroll
    for (int i = 0; i < 16; i++) { float d = v[i] - mu; s2 += d * d; }
    U.b.red[r][q][1] = s2;
    __syncthreads();
    float var = (U.b.red[r][0][1] + U.b.red[r][1][1]
               + U.b.red[r][2][1] + U.b.red[r][3][1]) * (1.f / 64.f);
    float rs = rsqrtf(var + 1e-5f);
    if (n < NN) {
        size_t grow = (size_t)(b * T2C + t2) * NN + n;
        #pragma unroll
        for (int i4 = 0; i4 < 4; i4++) {
            int c = c0 + 4 * i4;
            float4 g4 = *(const float4*)(gamma + c);
            float4 be = *(const float4*)(beta + c);
            float4 o4;
            o4.x = (v[4*i4+0] - mu) * rs * g4.x + be.x;
            o4.y = (v[4*i4+1] - mu) * rs * g4.y + be.y;
            o4.z = (v[4*i4+2] - mu) * rs * g4.z + be.z;
            o4.w = (v[4*i4+3] - mu) * rs * g4.w + be.w;
            *(float4*)(out + grow * DD + c) = o4;
        }
    }
}

// ---------------------------------------------------------------------------
extern "C" void kernel_launch(void* const* d_in, const int* in_sizes, int n_in,
                              void* d_out, int out_size, void* d_ws, size_t ws_size,
                              hipStream_t stream) {
    const float* feat    = (const float*)d_in[0];
    const float* weights = (const float*)d_in[1];
    const float* w1      = (const float*)d_in[2];
    const float* b1      = (const float*)d_in[3];
    const float* w2      = (const float*)d_in[4];
    const float* b2      = (const float*)d_in[5];
    const float* gamma   = (const float*)d_in[6];
    const float* beta    = (const float*)d_in[7];
    float* out = (float*)d_out;

    float* sigw   = (float*)d_ws;                   // 64
    float* invn   = sigw + 64;                      // 57600
    float* tspart = invn + BB * TT * NN;            // 960*64 = 61440
    f16*   w1f    = (f16*)(tspart + 960 * 64);      // 4096 f16
    f16*   w2f    = w1f + 4096;                     // 4096 f16

    k_prep<<<BB * TT * 5 + 1, 256, 0, stream>>>(feat, weights, w1, w2,
                                                sigw, invn, tspart, w1f, w2f);
    k_fused<<<NW * 5, 256, 0, stream>>>(feat, sigw, invn, tspart, w1f, w2f,
                                        b1, b2, gamma, beta, out);
}

// Round 10
// 131.961 us; speedup vs baseline: 1.4169x; 1.0928x over previous
//
#include <hip/hip_runtime.h>
#include <math.h>

#define BB  16
#define TT  12
#define T2C 10
#define NN  300
#define DD  64
#define M3  900   // 3*NN
#define NW  (BB*T2C)

typedef _Float16 f16;
typedef __attribute__((ext_vector_type(8)))  _Float16 f16x8;
typedef __attribute__((ext_vector_type(16))) float    f32x16;

#define KS 72   // fp16 row stride (144 B)

static __device__ inline unsigned pk2(f16 a, f16 b) {
    union { f16 h[2]; unsigned u; } x; x.h[0] = a; x.h[1] = b; return x.u;
}

// ---------------------------------------------------------------------------
// k_prep (r9-verified): blk < 960: invn (16-lane row reduces, 4 rows/wave-iter)
// + per-chunk tsum partials (no atomics). blk == 960: sigw + w1/w2 -> MFMA
// A-fragment order (fp16) in global.
// ---------------------------------------------------------------------------
__global__ __launch_bounds__(256) void k_prep(const float* __restrict__ feat,
                                              const float* __restrict__ weights,
                                              const float* __restrict__ w1,
                                              const float* __restrict__ w2,
                                              float* __restrict__ sigw,
                                              float* __restrict__ invn,
                                              float* __restrict__ tspart,
                                              f16* __restrict__ w1f,
                                              f16* __restrict__ w2f) {
    int blk = blockIdx.x;
    int tid = threadIdx.x;

    if (blk == BB * TT * 5) {
        if (tid < 64) sigw[tid] = 1.0f / (1.0f + expf(-weights[tid]));
        for (int p = tid; p < 1024; p += 256) {
            int lane = p & 63, s = p >> 6;
            int mat = s >> 3, loc = s & 7, ct = loc >> 2, ks = loc & 3;
            int hcol = ct * 32 + (lane & 31);
            const float* w = mat ? w2 : w1;
            f16* dst = (mat ? w2f : w1f) + ((size_t)loc * 64 + lane) * 8;
            f16x8 v;
            #pragma unroll
            for (int j = 0; j < 8; j++) {
                int d = ks * 16 + 8 * (lane >> 5) + j;
                v[j] = (f16)w[d * DD + hcol];
            }
            *(f16x8*)dst = v;
        }
        return;
    }

    __shared__ float part[4][64];
    int bt = blk / 5, ch = blk % 5;
    int row0 = bt * NN + ch * 60;
    int w = tid >> 6, lane = tid & 63;
    int r16 = lane >> 4, c4 = lane & 15;

    float4 wv = *(const float4*)(weights + c4 * 4);
    float4 sg;
    sg.x = 1.0f / (1.0f + expf(-wv.x)); sg.y = 1.0f / (1.0f + expf(-wv.y));
    sg.z = 1.0f / (1.0f + expf(-wv.z)); sg.w = 1.0f / (1.0f + expf(-wv.w));

    float ax = 0.f, ay = 0.f, az = 0.f, aw = 0.f;
    for (int g = w; g < 15; g += 4) {
        int row = row0 + g * 4 + r16;
        float4 f = *(const float4*)(feat + (size_t)row * DD + c4 * 4);
        float xx = f.x * sg.x, xy = f.y * sg.y, xz = f.z * sg.z, xw = f.w * sg.w;
        float ss = xx * xx + xy * xy + xz * xz + xw * xw;
        ss += __shfl_xor(ss, 1, 64);
        ss += __shfl_xor(ss, 2, 64);
        ss += __shfl_xor(ss, 4, 64);
        ss += __shfl_xor(ss, 8, 64);
        float in = 1.0f / fmaxf(sqrtf(ss), 1e-12f);
        if (c4 == 0) invn[row] = in;
        ax += f.x * in; ay += f.y * in; az += f.z * in; aw += f.w * in;
    }
    #pragma unroll
    for (int off = 16; off <= 32; off <<= 1) {
        ax += __shfl_xor(ax, off, 64); ay += __shfl_xor(ay, off, 64);
        az += __shfl_xor(az, off, 64); aw += __shfl_xor(aw, off, 64);
    }
    if (r16 == 0) {
        float* p = &part[w][c4 * 4];
        p[0] = ax * sg.x; p[1] = ay * sg.y; p[2] = az * sg.z; p[3] = aw * sg.w;
    }
    __syncthreads();
    if (tid < 64)
        tspart[(size_t)blk * 64 + tid] =
            part[0][tid] + part[1][tid] + part[2][tid] + part[3][tid];
}

// ---------------------------------------------------------------------------
// k_fused v4: r7's verified staging/compute layout, software-pipelined:
//   epoch kt: [issue kt+1 global loads] -> phase1 (Kf LDS) -> Sl write
//   -> barrier -> phase2 (Sl,Vt) -> barrier -> stage kt+1 Kf/Vt from regs
//   -> barrier.    (3 barriers/kt; load latency hidden behind 8 MFMAs)
// + in-LDS FFN/LayerNorm tail + XCD swizzle + tspart deg basis.
// ---------------------------------------------------------------------------
__global__ __launch_bounds__(256) void k_fused(const float* __restrict__ feat,
                                               const float* __restrict__ sigw,
                                               const float* __restrict__ invn,
                                               const float* __restrict__ tspart,
                                               const f16* __restrict__ w1f,
                                               const f16* __restrict__ w2f,
                                               const float* __restrict__ b1,
                                               const float* __restrict__ b2,
                                               const float* __restrict__ gamma,
                                               const float* __restrict__ beta,
                                               float* __restrict__ out) {
    __shared__ union __align__(16) {
        struct __align__(16) {              // aggregation stage (~28 KB)
            f16 Kf[64 * KS];
            f16 Vt[64 * KS];
            f16 Sl[64 * KS];
            float degp[64][4];
        } a;
        struct __align__(16) {              // FFN stage (~29.5 KB)
            float Ol[64 * 68];
            f16 Hl[64 * KS];
            float red[64][4][2];
            float rmax[64][4];
            float scls[64];
            float isls[64];
        } b;
    } U;
    __shared__ float degs[64];
    __shared__ float ksumL[64];

    int blk = blockIdx.x;
    int wdw = blk % NW;    // XCD swizzle: a window's 5 blocks are 160 apart
    int rb  = blk / NW;
    int t2 = wdw % T2C, b = wdw / T2C;
    int n0 = rb * 64;
    int qrow0 = (b * TT + t2 + 2) * NN;
    int krow0 = (b * TT + t2) * NN;
    int tid = threadIdx.x;
    int wv = tid >> 6, lane = tid & 63;
    int l31 = lane & 31, lh = lane >> 5;
    int nt = wv & 1;   // phase1 n-block == phase2 row-block
    int mt = wv >> 1;  // phase1 m-tile  == phase2 d-block

    // ---- ksumL[d] = sum of the window's 15 tspart chunk rows (fp32) ----
    if (tid < 64) {
        const float* tp = tspart + (size_t)(b * TT + t2) * 5 * 64 + tid;
        float s = 0.f;
        #pragma unroll
        for (int j = 0; j < 15; j++) s += tp[j * 64];
        ksumL[tid] = s;
    }

    // ---- Q'' B-frags in registers: feat_q * sigw^2 * invn_q ----
    f16x8 qf[4];
    {
        int nloc = n0 + nt * 32 + l31;
        bool ok = nloc < NN;
        int gr = qrow0 + (ok ? nloc : 0);
        float in = ok ? invn[gr] : 0.f;
        #pragma unroll
        for (int ks = 0; ks < 4; ks++) {
            int c0 = ks * 16 + 8 * lh;
            float4 f0 = *(const float4*)(feat + (size_t)gr * DD + c0);
            float4 f1 = *(const float4*)(feat + (size_t)gr * DD + c0 + 4);
            float4 s0 = *(const float4*)(sigw + c0);
            float4 s1 = *(const float4*)(sigw + c0 + 4);
            f16x8 qv;
            qv[0] = (f16)(f0.x * s0.x * s0.x * in); qv[1] = (f16)(f0.y * s0.y * s0.y * in);
            qv[2] = (f16)(f0.z * s0.z * s0.z * in); qv[3] = (f16)(f0.w * s0.w * s0.w * in);
            qv[4] = (f16)(f1.x * s1.x * s1.x * in); qv[5] = (f16)(f1.y * s1.y * s1.y * in);
            qv[6] = (f16)(f1.z * s1.z * s1.z * in); qv[7] = (f16)(f1.w * s1.w * s1.w * in);
            qf[ks] = qv;
        }
    }
    __syncthreads();   // ksumL visible

    // ---- deg partials: deg[n] = (feat[n]*sigw . ksumL) * invn[n] ----
    {
        int r = tid >> 2, qd = (tid & 3) * 16;
        float p = 0.f;
        if (n0 + r < NN) {
            int gr = qrow0 + n0 + r;
            float in = invn[gr];
            const float4* f4 = (const float4*)(feat + (size_t)gr * DD + qd);
            const float4* s4 = (const float4*)(sigw + qd);
            const float4* k4 = (const float4*)(ksumL + qd);
            #pragma unroll
            for (int i = 0; i < 4; i++) {
                float4 f = f4[i], s = s4[i], k = k4[i];
                p += f.x * s.x * k.x + f.y * s.y * k.y
                   + f.z * s.z * k.z + f.w * s.w * k.w;
            }
            p *= in;
        }
        U.a.degp[r][tid & 3] = p;
    }

    int mrow_s = (tid & 31) * 2;     // staging m-pair
    int dblk_s = (tid >> 5) * 8;     // staging 8-col block

    // ---- prologue: load tile 0 into regs (rows 0..63 always < M3) ----
    float4 A0, A1, B0, B1;
    float i0, i1;
    {
        int g0 = krow0 + mrow_s;
        A0 = *(const float4*)(feat + (size_t)g0 * DD + dblk_s);
        A1 = *(const float4*)(feat + (size_t)g0 * DD + dblk_s + 4);
        B0 = *(const float4*)(feat + (size_t)(g0 + 1) * DD + dblk_s);
        B1 = *(const float4*)(feat + (size_t)(g0 + 1) * DD + dblk_s + 4);
        i0 = invn[g0]; i1 = invn[g0 + 1];
    }
    __syncthreads();   // degp visible
    if (tid < 64)
        degs[tid] = U.a.degp[tid][0] + U.a.degp[tid][1]
                  + U.a.degp[tid][2] + U.a.degp[tid][3];
    // stage tile 0
    {
        f16x8 r0, r1;
        r0[0]=(f16)A0.x; r0[1]=(f16)A0.y; r0[2]=(f16)A0.z; r0[3]=(f16)A0.w;
        r0[4]=(f16)A1.x; r0[5]=(f16)A1.y; r0[6]=(f16)A1.z; r0[7]=(f16)A1.w;
        r1[0]=(f16)B0.x; r1[1]=(f16)B0.y; r1[2]=(f16)B0.z; r1[3]=(f16)B0.w;
        r1[4]=(f16)B1.x; r1[5]=(f16)B1.y; r1[6]=(f16)B1.z; r1[7]=(f16)B1.w;
        *(f16x8*)&U.a.Kf[mrow_s * KS + dblk_s] = r0;
        *(f16x8*)&U.a.Kf[(mrow_s + 1) * KS + dblk_s] = r1;
        float a[8] = {A0.x, A0.y, A0.z, A0.w, A1.x, A1.y, A1.z, A1.w};
        float c[8] = {B0.x, B0.y, B0.z, B0.w, B1.x, B1.y, B1.z, B1.w};
        #pragma unroll
        for (int i = 0; i < 8; i++)
            *(unsigned*)&U.a.Vt[(dblk_s + i) * KS + mrow_s] =
                pk2((f16)(a[i] * i0), (f16)(c[i] * i1));
    }
    __syncthreads();   // tile 0 staged

    f32x16 acc;
    #pragma unroll
    for (int i = 0; i < 16; i++) acc[i] = 0.f;

    for (int kt = 0; kt < 15; kt++) {
        bool hn = kt < 14;
        // ---- issue kt+1 loads (consumed post-phase2: latency hidden) ----
        if (hn) {
            int m0n = (kt + 1) * 64;
            int gm0 = m0n + mrow_s, gm1 = gm0 + 1;
            bool ok0 = gm0 < M3, ok1 = gm1 < M3;
            int g0 = krow0 + (ok0 ? gm0 : 0);
            int g1 = krow0 + (ok1 ? gm1 : 0);
            A0 = *(const float4*)(feat + (size_t)g0 * DD + dblk_s);
            A1 = *(const float4*)(feat + (size_t)g0 * DD + dblk_s + 4);
            B0 = *(const float4*)(feat + (size_t)g1 * DD + dblk_s);
            B1 = *(const float4*)(feat + (size_t)g1 * DD + dblk_s + 4);
            i0 = ok0 ? invn[g0] : 0.f;
            i1 = ok1 ? invn[g1] : 0.f;
            if (!ok0) { A0 = make_float4(0,0,0,0); A1 = A0; }
            if (!ok1) { B0 = make_float4(0,0,0,0); B1 = B0; }
        }

        // ---- phase1: S''^T tile (m-rows mt*32.., n-cols nt*32..) ----
        f32x16 c1;
        #pragma unroll
        for (int i = 0; i < 16; i++) c1[i] = 0.f;
        #pragma unroll
        for (int ks = 0; ks < 4; ks++) {
            f16x8 af = *(const f16x8*)&U.a.Kf[(mt * 32 + l31) * KS + ks * 16 + 8 * lh];
            c1 = __builtin_amdgcn_mfma_f32_32x32x16_f16(af, qf[ks], c1, 0, 0, 0);
        }
        #pragma unroll
        for (int g = 0; g < 4; g++) {
            union { f16 h[4]; uint2 u; } p;
            p.h[0] = (f16)c1[4 * g + 0]; p.h[1] = (f16)c1[4 * g + 1];
            p.h[2] = (f16)c1[4 * g + 2]; p.h[3] = (f16)c1[4 * g + 3];
            *(uint2*)&U.a.Sl[(nt * 32 + l31) * KS + mt * 32 + 8 * g + 4 * lh] = p.u;
        }
        __syncthreads();   // Sl visible; all phase1 Kf reads done

        // ---- phase2: acc(n-block nt, d-block mt) += S . V ----
        #pragma unroll
        for (int ms = 0; ms < 4; ms++) {
            f16x8 sa = *(const f16x8*)&U.a.Sl[(nt * 32 + l31) * KS + ms * 16 + 8 * lh];
            f16x8 vb = *(const f16x8*)&U.a.Vt[(mt * 32 + l31) * KS + ms * 16 + 8 * lh];
            acc = __builtin_amdgcn_mfma_f32_32x32x16_f16(sa, vb, acc, 0, 0, 0);
        }
        __syncthreads();   // phase2 reads of Sl/Vt done

        // ---- stage kt+1 from regs (packed b32 Vt writes) ----
        if (hn) {
            f16x8 r0, r1;
            r0[0]=(f16)A0.x; r0[1]=(f16)A0.y; r0[2]=(f16)A0.z; r0[3]=(f16)A0.w;
            r0[4]=(f16)A1.x; r0[5]=(f16)A1.y; r0[6]=(f16)A1.z; r0[7]=(f16)A1.w;
            r1[0]=(f16)B0.x; r1[1]=(f16)B0.y; r1[2]=(f16)B0.z; r1[3]=(f16)B0.w;
            r1[4]=(f16)B1.x; r1[5]=(f16)B1.y; r1[6]=(f16)B1.z; r1[7]=(f16)B1.w;
            *(f16x8*)&U.a.Kf[mrow_s * KS + dblk_s] = r0;
            *(f16x8*)&U.a.Kf[(mrow_s + 1) * KS + dblk_s] = r1;
            float a[8] = {A0.x, A0.y, A0.z, A0.w, A1.x, A1.y, A1.z, A1.w};
            float c[8] = {B0.x, B0.y, B0.z, B0.w, B1.x, B1.y, B1.z, B1.w};
            #pragma unroll
            for (int i = 0; i < 8; i++)
                *(unsigned*)&U.a.Vt[(dblk_s + i) * KS + mrow_s] =
                    pk2((f16)(a[i] * i0), (f16)(c[i] * i1));
        }
        __syncthreads();   // next tile staged
    }

    // ================= FFN stage (in-LDS handoff; r7-verified) =============
    int ct = wv & 1, rt = wv >> 1;
    f16x8 w1a[4], w2a[4];
    #pragma unroll
    for (int ks = 0; ks < 4; ks++) {
        w1a[ks] = *(const f16x8*)(w1f + ((size_t)(ct * 4 + ks) * 64 + lane) * 8);
        w2a[ks] = *(const f16x8*)(w2f + ((size_t)(ct * 4 + ks) * 64 + lane) * 8);
    }

    // agg = acc * dinv -> Ol[row][col] fp32
    {
        int dcol = mt * 32 + l31;
        #pragma unroll
        for (int g = 0; g < 4; g++) {
            #pragma unroll
            for (int i = 0; i < 4; i++) {
                int rl = nt * 32 + 8 * g + 4 * lh + i;
                float dg = degs[rl];
                float dinv = (dg == 0.f) ? 0.f : 1.f / dg;
                U.b.Ol[rl * 68 + dcol] = acc[4 * g + i] * dinv;
            }
        }
    }
    __syncthreads();

    int r = tid >> 2, q = tid & 3, c0 = q * 16;
    {
        float mx = 0.f;
        #pragma unroll
        for (int i = 0; i < 16; i += 4) {
            float4 f = *(const float4*)&U.b.Ol[r * 68 + c0 + i];
            mx = fmaxf(mx, fmaxf(fmaxf(fabsf(f.x), fabsf(f.y)),
                                 fmaxf(fabsf(f.z), fabsf(f.w))));
        }
        U.b.rmax[r][q] = mx;
    }
    __syncthreads();
    if (q == 0) {
        float rm = fmaxf(fmaxf(U.b.rmax[r][0], U.b.rmax[r][1]),
                         fmaxf(U.b.rmax[r][2], U.b.rmax[r][3]));
        int e = 0;
        frexpf(rm, &e);
        U.b.scls[r] = (rm > 1.f) ? exp2f((float)-e) : 1.f;
        U.b.isls[r] = (rm > 1.f) ? exp2f((float)e) : 1.f;
    }
    __syncthreads();

    // phase A: h_s^T = w1^T . A_s^T  (A_s read from Ol, scaled on the fly)
    float sclrow = U.b.scls[rt * 32 + l31];
    f32x16 hc;
    #pragma unroll
    for (int i = 0; i < 16; i++) hc[i] = 0.f;
    #pragma unroll
    for (int ks = 0; ks < 4; ks++) {
        const float* prow = &U.b.Ol[(rt * 32 + l31) * 68 + ks * 16 + 8 * lh];
        float4 pa = *(const float4*)prow;
        float4 pb = *(const float4*)(prow + 4);
        f16x8 bf;
        bf[0] = (f16)(pa.x * sclrow); bf[1] = (f16)(pa.y * sclrow);
        bf[2] = (f16)(pa.z * sclrow); bf[3] = (f16)(pa.w * sclrow);
        bf[4] = (f16)(pb.x * sclrow); bf[5] = (f16)(pb.y * sclrow);
        bf[6] = (f16)(pb.z * sclrow); bf[7] = (f16)(pb.w * sclrow);
        hc = __builtin_amdgcn_mfma_f32_32x32x16_f16(w1a[ks], bf, hc, 0, 0, 0);
    }
    #pragma unroll
    for (int g = 0; g < 4; g++) {
        union { f16 h[4]; uint2 u; } p;
        #pragma unroll
        for (int i = 0; i < 4; i++) {
            int hcol = ct * 32 + 8 * g + 4 * lh + i;
            p.h[i] = (f16)fmaxf(hc[4 * g + i] + sclrow * b1[hcol], 0.f);
        }
        *(uint2*)&U.b.Hl[(rt * 32 + l31) * KS + ct * 32 + 8 * g + 4 * lh] = p.u;
    }
    __syncthreads();

    // phase B: o_s^T = w2^T . h_s^T ; result overwrites Ol (agg dead)
    f32x16 oc;
    #pragma unroll
    for (int i = 0; i < 16; i++) oc[i] = 0.f;
    #pragma unroll
    for (int ks = 0; ks < 4; ks++) {
        f16x8 bf = *(const f16x8*)&U.b.Hl[(rt * 32 + l31) * KS + ks * 16 + 8 * lh];
        oc = __builtin_amdgcn_mfma_f32_32x32x16_f16(w2a[ks], bf, oc, 0, 0, 0);
    }
    __syncthreads();
    #pragma unroll
    for (int g = 0; g < 4; g++) {
        float4 o4 = make_float4(oc[4*g+0], oc[4*g+1], oc[4*g+2], oc[4*g+3]);
        *(float4*)&U.b.Ol[(rt * 32 + l31) * 68 + ct * 32 + 8 * g + 4 * lh] = o4;
    }
    __syncthreads();

    // epilogue: s = o_s/s_n + b2 + residual; LayerNorm; guarded store
    int n = n0 + r;
    int nn = (n < NN) ? n : (NN - 1);
    size_t frow = (size_t)(b * TT + t2 + 2) * NN + nn;
    float is = U.b.isls[r];
    float v[16];
    float sum = 0.f;
    #pragma unroll
    for (int i = 0; i < 16; i++) {
        int c = c0 + i;
        float x = U.b.Ol[r * 68 + c] * is + b2[c] + feat[frow * DD + c];
        v[i] = x; sum += x;
    }
    U.b.red[r][q][0] = sum;
    __syncthreads();
    float mu = (U.b.red[r][0][0] + U.b.red[r][1][0]
              + U.b.red[r][2][0] + U.b.red[r][3][0]) * (1.f / 64.f);
    float s2 = 0.f;
    #pragma unroll
    for (int i = 0; i < 16; i++) { float d = v[i] - mu; s2 += d * d; }
    U.b.red[r][q][1] = s2;
    __syncthreads();
    float var = (U.b.red[r][0][1] + U.b.red[r][1][1]
               + U.b.red[r][2][1] + U.b.red[r][3][1]) * (1.f / 64.f);
    float rs = rsqrtf(var + 1e-5f);
    if (n < NN) {
        size_t grow = (size_t)(b * T2C + t2) * NN + n;
        #pragma unroll
        for (int i4 = 0; i4 < 4; i4++) {
            int c = c0 + 4 * i4;
            float4 g4 = *(const float4*)(gamma + c);
            float4 be = *(const float4*)(beta + c);
            float4 o4;
            o4.x = (v[4*i4+0] - mu) * rs * g4.x + be.x;
            o4.y = (v[4*i4+1] - mu) * rs * g4.y + be.y;
            o4.z = (v[4*i4+2] - mu) * rs * g4.z + be.z;
            o4.w = (v[4*i4+3] - mu) * rs * g4.w + be.w;
            *(float4*)(out + grow * DD + c) = o4;
        }
    }
}

// ---------------------------------------------------------------------------
extern "C" void kernel_launch(void* const* d_in, const int* in_sizes, int n_in,
                              void* d_out, int out_size, void* d_ws, size_t ws_size,
                              hipStream_t stream) {
    const float* feat    = (const float*)d_in[0];
    const float* weights = (const float*)d_in[1];
    const float* w1      = (const float*)d_in[2];
    const float* b1      = (const float*)d_in[3];
    const float* w2      = (const float*)d_in[4];
    const float* b2      = (const float*)d_in[5];
    const float* gamma   = (const float*)d_in[6];
    const float* beta    = (const float*)d_in[7];
    float* out = (float*)d_out;

    float* sigw   = (float*)d_ws;                   // 64
    float* invn   = sigw + 64;                      // 57600
    float* tspart = invn + BB * TT * NN;            // 960*64 = 61440
    f16*   w1f    = (f16*)(tspart + 960 * 64);      // 4096 f16
    f16*   w2f    = w1f + 4096;                     // 4096 f16

    k_prep<<<BB * TT * 5 + 1, 256, 0, stream>>>(feat, weights, w1, w2,
                                                sigw, invn, tspart, w1f, w2f);
    k_fused<<<NW * 5, 256, 0, stream>>>(feat, sigw, invn, tspart, w1f, w2f,
                                        b1, b2, gamma, beta, out);
}